// Round 11
// baseline (618.819 us; speedup 1.0000x reference)
//
#include <hip/hip_runtime.h>
#include <stdint.h>

#define NEGV (-1000000000.0f)

typedef float  f32x4  __attribute__((ext_vector_type(4)));
typedef __bf16 bf16x8 __attribute__((ext_vector_type(8)));

__device__ __forceinline__ unsigned short f2bf(float f){
  union { float f; unsigned u; } v; v.f = f;
  unsigned r = v.u + 0x7FFFu + ((v.u >> 16) & 1u);
  return (unsigned short)(r >> 16);
}
__device__ __forceinline__ unsigned packbf2(float a, float b){
  return (unsigned)f2bf(a) | ((unsigned)f2bf(b) << 16);
}
__device__ __forceinline__ void gl_lds16(const void* g, const char* l){
  __builtin_amdgcn_global_load_lds(
      (const __attribute__((address_space(1))) void*)g,
      (__attribute__((address_space(3))) void*)(unsigned)(uintptr_t)l,
      16, 0, 0);
}

// ws layouts (per batch, 128 KB each) — FRAGMENT-CONTIGUOUS:
//  qbf : frag[ch][ks][j][64B]   ch=k/64, ks=(k/32)&1, j=0..127
//  qtbf: frag[hch][ks][hr][64B] hch=h/64, ks=j/32,    hr=h&63

// ---------------- K0: Q -> packed bf16 fragments, s_q partials -------------
__global__ __launch_bounds__(256) void k0_prep(const float* __restrict__ Q,
                                               const float* __restrict__ w,
                                               char* __restrict__ qbf,
                                               char* __restrict__ qtbf,
                                               float* __restrict__ sq_part)
{
  __shared__ float tile[128][129];
  __shared__ float sqs[128];
  const int bid = blockIdx.x, t = threadIdx.x;
  const int b = bid >> 2, hc = bid & 3;
  if (t < 128) sqs[t] = 0.f;
  __syncthreads();
  for (int it = 0; it < 16; ++it){
    int idx = it*256 + t;
    int j = idx >> 5, h4 = idx & 31;
    const f32x4 q4 = *(const f32x4*)(Q + ((size_t)b*128 + j)*512 + hc*128 + h4*4);
    *(f32x4*)(&tile[j][h4*4]) = q4;
    unsigned lo = packbf2(q4.x, q4.y), hi = packbf2(q4.z, q4.w);
    int k = hc*128 + h4*4;
    int o = (k >> 6)*16384 + (((k >> 5) & 1))*8192 + j*64 + (k & 31)*2;
    char* dst = qbf + (size_t)b*131072 + o;
    *(unsigned*)dst = lo; *(unsigned*)(dst + 4) = hi;
    const float* w2 = w + 512 + k;
    float p = q4.x*w2[0] + q4.y*w2[1] + q4.z*w2[2] + q4.w*w2[3];
    for (int s = 16; s > 0; s >>= 1) p += __shfl_down(p, s, 32);
    if ((t & 31) == 0) sqs[j] += p;
  }
  __syncthreads();
  for (int it = 0; it < 32; ++it){
    int idx = it*256 + t;
    int hr = idx >> 6, j2 = idx & 63;
    float a = tile[j2*2][hr], c = tile[j2*2+1][hr];
    int h = hc*128 + hr;
    int o = (h >> 6)*16384 + (j2 >> 4)*4096 + (h & 63)*64 + (j2 & 15)*4;
    *(unsigned*)(qtbf + (size_t)b*131072 + o) = packbf2(a, c);
  }
  if (t < 128) sq_part[(size_t)(b*4 + hc)*128 + t] = sqs[t];
}

// ---- K1: 4 tiles/block, double-buffered C, T14 async-STAGE across tiles ---
__global__ __launch_bounds__(512, 4) void k1_main(
    const float* __restrict__ C, const int* __restrict__ qmask,
    const float* __restrict__ w, const float* __restrict__ sq_part,
    const char* __restrict__ qbf, const char* __restrict__ qtbf,
    float* __restrict__ out, float* __restrict__ num_part,
    float* __restrict__ den_part)
{
  __shared__ __align__(16) char lds_c[2][32768]; // C tiles, swizzled rows
  __shared__ __align__(16) char cw[4096];        // P: 16 rows x 256 B
  __shared__ float w1l[512], w3l[512];
  __shared__ float sqf[128];
  __shared__ int   msk[128];
  __shared__ float exf[16];
  __shared__ float mh[8][16], sh[8][16];

  const int t = threadIdx.x;
  const int bid = blockIdx.x;
  const int xcd = bid & 7, jj = bid >> 3;            // 512 = 8 x 64
  const int b = xcd*4 + (jj >> 4);                   // batch-per-XCD locality
  const int itile0 = (jj & 15)*4;
  const int wv = t >> 6, ln = t & 63;
  const int g = ln >> 4, c16 = ln & 15;
  const int iloc = c16;
  const int swz = ((iloc & 7) << 4) | (((iloc >> 3) & 1) << 7);
  const int srow = t >> 5;                            // stage row (64B/thread)
  const int smsw = ((srow & 7) << 4) | (((srow >> 3) & 1) << 7);

  // ---- prologue: gload_lds stage tile0 into buf0 (pre-swizzled source) ----
  {
    const char* ct = (const char*)(C + (size_t)(b*1024 + itile0*16)*512);
    #pragma unroll
    for (int r = 0; r < 4; ++r){
      const int ob  = wv*4096 + r*1024;
      const int row = ob >> 11;
      const int msw = ((row & 7) << 4) | (((row >> 3) & 1) << 7);
      gl_lds16(ct + ob + ((ln << 4) ^ msw), &lds_c[0][0] + ob);
    }
  }
  if (t < 128){
    sqf[t] = sq_part[(size_t)(b*4 + 0)*128 + t] + sq_part[(size_t)(b*4 + 1)*128 + t]
           + sq_part[(size_t)(b*4 + 2)*128 + t] + sq_part[(size_t)(b*4 + 3)*128 + t];
    msk[t] = qmask[b*128 + t];
  }
  w1l[t] = w[t];
  w3l[t] = w[1024 + t];
  __syncthreads();

  const char* qsrc  = qbf  + (size_t)b * 131072;
  const char* qtsrc = qtbf + (size_t)b * 131072;

  for (int tt = 0; tt < 4; ++tt){
    const char* buf = &lds_c[tt & 1][0];
    const int i0 = (itile0 + tt)*16;
    const size_t rowb = (size_t)(b*1024 + i0 + iloc);

    // ---- S-phase: wave wv computes D[j][i] for j in [wv*16, wv*16+16) ----
    float scp = 0.f;
    f32x4 acc = {};
    #pragma unroll
    for (int ch = 0; ch < 8; ++ch){
      #pragma unroll
      for (int ks = 0; ks < 2; ++ks){
        const int k0 = ch*64 + ks*32 + g*8;
        const int lo = iloc*2048 + k0*4;
        const f32x4 cA  = *(const f32x4*)(buf + (lo ^ swz));
        const f32x4 cB  = *(const f32x4*)(buf + ((lo + 16) ^ swz));
        const f32x4 w3A = *(const f32x4*)(w3l + k0);
        const f32x4 w3B = *(const f32x4*)(w3l + k0 + 4);
        const f32x4 w1A = *(const f32x4*)(w1l + k0);
        const f32x4 w1B = *(const f32x4*)(w1l + k0 + 4);
        scp += cA.x*w1A.x + cA.y*w1A.y + cA.z*w1A.z + cA.w*w1A.w
             + cB.x*w1B.x + cB.y*w1B.y + cB.z*w1B.z + cB.w*w1B.w;
        bf16x8 bv;
        bv[0] = (__bf16)(cA.x*w3A.x); bv[1] = (__bf16)(cA.y*w3A.y);
        bv[2] = (__bf16)(cA.z*w3A.z); bv[3] = (__bf16)(cA.w*w3A.w);
        bv[4] = (__bf16)(cB.x*w3B.x); bv[5] = (__bf16)(cB.y*w3B.y);
        bv[6] = (__bf16)(cB.z*w3B.z); bv[7] = (__bf16)(cB.w*w3B.w);
        const int j = wv*16 + c16;
        bf16x8 av = *(const bf16x8*)(qsrc + ch*16384 + ks*8192 + j*64 + g*16);
        acc = __builtin_amdgcn_mfma_f32_16x16x32_bf16(av, bv, acc, 0, 0, 0);
      }
    }

    // ---- T14 issue-early: next tile's C -> regs (linear source) ----
    f32x4 rl0, rl1, rl2, rl3;
    if (tt < 3){
      const float* cnx = C + (size_t)(b*1024 + (itile0 + tt + 1)*16)*512;
      rl0 = *(const f32x4*)(cnx + t*16);
      rl1 = *(const f32x4*)(cnx + t*16 + 4);
      rl2 = *(const f32x4*)(cnx + t*16 + 8);
      rl3 = *(const f32x4*)(cnx + t*16 + 12);
      __builtin_amdgcn_sched_barrier(0);   // pin issue point (no sinking)
    }

    scp += __shfl_xor(scp, 16);
    scp += __shfl_xor(scp, 32);
    const float sc = scp;

    // ---- wave-local softmax eighth ----
    float m = -3.0e38f;
    #pragma unroll
    for (int r = 0; r < 4; ++r){
      int j = wv*16 + g*4 + r;
      float v = msk[j] ? (acc[r] + sc + sqf[j]) : NEGV;
      acc[r] = v;
      m = fmaxf(m, v);
    }
    m = fmaxf(m, __shfl_xor(m, 16));
    m = fmaxf(m, __shfl_xor(m, 32));
    float s = 0.f;
    #pragma unroll
    for (int r = 0; r < 4; ++r){
      float e = __expf(acc[r] - m);
      acc[r] = e; s += e;
    }
    s += __shfl_xor(s, 16);
    s += __shfl_xor(s, 32);
    if (g == 0){ mh[wv][iloc] = m; sh[wv][iloc] = s; }
    __syncthreads();

    // ---- 8-way combine ----
    float mF = mh[0][iloc];
    #pragma unroll
    for (int q = 1; q < 8; ++q) mF = fmaxf(mF, mh[q][iloc]);
    float sF = 0.f;
    #pragma unroll
    for (int q = 0; q < 8; ++q) sF += sh[q][iloc]*__expf(mh[q][iloc] - mF);
    const float scale = __expf(m - mF) / sF;
    {
      uint64_t pk = (uint64_t)packbf2(acc[0]*scale, acc[1]*scale)
                  | ((uint64_t)packbf2(acc[2]*scale, acc[3]*scale) << 32);
      *(uint64_t*)(cw + ((iloc*256 + wv*32 + g*8) ^ ((iloc & 7) << 4))) = pk;
    }
    if (wv == 0 && g == 0) exf[iloc] = __expf(mF);
    __syncthreads();

    // ---- PV: wave wv covers h in [wv*64, wv*64+64); fused epilogue ----
    bf16x8 pb[4];
    #pragma unroll
    for (int ks = 0; ks < 4; ++ks)
      pb[ks] = *(const bf16x8*)(cw + ((iloc*256 + ks*64 + g*16) ^ ((iloc & 7) << 4)));

    f32x4 a2[4] = {};
    #pragma unroll
    for (int nf = 0; nf < 4; ++nf){
      int hr = nf*16 + c16;
      #pragma unroll
      for (int ks = 0; ks < 4; ++ks){
        bf16x8 qa = *(const bf16x8*)(qtsrc + wv*16384 + ks*4096 + hr*64 + g*16);
        a2[nf] = __builtin_amdgcn_mfma_f32_16x16x32_bf16(qa, pb[ks], a2[nf], 0, 0, 0);
      }
    }
    #pragma unroll
    for (int nf = 0; nf < 4; ++nf){
      int h = wv*64 + nf*16 + g*4;
      const int lo = iloc*2048 + h*4;
      const f32x4 c4 = *(const f32x4*)(buf + (lo ^ swz));
      f32x4 av = a2[nf];
      *(f32x4*)(out + rowb*2048 + h)        = c4;        // C copy
      *(f32x4*)(out + rowb*2048 + 512 + h)  = av;        // A
      f32x4 ca = av * c4;
      *(f32x4*)(out + rowb*2048 + 1024 + h) = ca;        // C*A
    }

    // ---- T14 write-late: stage next tile into the idle buffer ----
    if (tt < 3){
      char* db = &lds_c[(tt & 1) ^ 1][0];
      *(f32x4*)(db + ((t*64 +  0) ^ smsw)) = rl0;
      *(f32x4*)(db + ((t*64 + 16) ^ smsw)) = rl1;
      *(f32x4*)(db + ((t*64 + 32) ^ smsw)) = rl2;
      *(f32x4*)(db + ((t*64 + 48) ^ smsw)) = rl3;
    }

    // ---- B_vec partials (from current buf) ----
    float n0 = 0.f;
    #pragma unroll
    for (int i2 = 0; i2 < 16; ++i2){
      const int ms = ((i2 & 7) << 4) | (((i2 >> 3) & 1) << 7);
      n0 += exf[i2] * *(const float*)(buf + ((i2*2048 + t*4) ^ ms));
    }
    num_part[((size_t)(b*64 + itile0 + tt))*512 + t] = n0;
    if (t < 16){
      float d = exf[t];
      d += __shfl_down(d, 8, 16); d += __shfl_down(d, 4, 16);
      d += __shfl_down(d, 2, 16); d += __shfl_down(d, 1, 16);
      if (t == 0) den_part[b*64 + itile0 + tt] = d;
    }
    __syncthreads();   // tile end: next buf visible; exf/cw reads complete
  }
}

// ---------------- K2: reduce partials -> B_vec ------------------------------
__global__ __launch_bounds__(256) void k2_bvec(const float* __restrict__ num_part,
                                               const float* __restrict__ den_part,
                                               float* __restrict__ bvec)
{
  int b = blockIdx.x, t = threadIdx.x;
  float d = 0.f;
  for (int k = 0; k < 64; ++k) d += den_part[b*64 + k];
  float inv = 1.0f / d;
  for (int h = t; h < 512; h += 256){
    float s = 0.f;
    for (int k = 0; k < 64; ++k) s += num_part[(size_t)(b*64 + k)*512 + h];
    bvec[b*512 + h] = s * inv;
  }
}

// ---------------- K3: write C*B_vec chunk -----------------------------------
__global__ __launch_bounds__(256) void k3_cout(const float* __restrict__ C,
                                               const float* __restrict__ bvec,
                                               float* __restrict__ out)
{
  int t = threadIdx.x;
  size_t row = (size_t)blockIdx.x*2 + (t >> 7);
  int col4 = t & 127;
  int b = (int)(row >> 10);
  const f32x4 c4 = *(const f32x4*)(C + row*512 + col4*4);
  const f32x4 bv = *(const f32x4*)(bvec + (size_t)b*512 + col4*4);
  f32x4 cb;
  cb.x = c4.x*bv.x; cb.y = c4.y*bv.y; cb.z = c4.z*bv.z; cb.w = c4.w*bv.w;
  *(f32x4*)(out + row*2048 + 1536 + col4*4) = cb;
}

extern "C" void kernel_launch(void* const* d_in, const int* in_sizes, int n_in,
                              void* d_out, int out_size, void* d_ws, size_t ws_size,
                              hipStream_t stream)
{
  const float* C     = (const float*)d_in[0];
  const float* Q     = (const float*)d_in[1];
  const int*   qmask = (const int*)d_in[2];
  const float* w     = (const float*)d_in[3];
  float* out = (float*)d_out;
  char*  ws  = (char*)d_ws;

  char*  qbf      = ws;                                    // 4 MB
  char*  qtbf     = ws + (4 << 20);                        // 4 MB
  float* sq_part  = (float*)(ws + (8 << 20));              // 64 KB
  float* num_part = (float*)(ws + (8 << 20) + (1 << 16));  // 4 MB
  float* den_part = (float*)(ws + (12 << 20) + (1 << 16)); // 8 KB
  float* bvec     = (float*)(ws + (12 << 20) + (1 << 16) + 8192); // 64 KB

  k0_prep<<<128, 256, 0, stream>>>(Q, w, qbf, qtbf, sq_part);
  k1_main<<<512, 512, 0, stream>>>(C, qmask, w, sq_part, qbf, qtbf,
                                   out, num_part, den_part);
  k2_bvec<<<32, 256, 0, stream>>>(num_part, den_part, bvec);
  k3_cout<<<16384, 256, 0, stream>>>(C, bvec, out);
}

// Round 12
// 235.179 us; speedup vs baseline: 2.6313x; 2.6313x over previous
//
#include <hip/hip_runtime.h>
#include <stdint.h>

#define NEGV (-1000000000.0f)

typedef float  f32x4  __attribute__((ext_vector_type(4)));
typedef __bf16 bf16x8 __attribute__((ext_vector_type(8)));

__device__ __forceinline__ unsigned short f2bf(float f){
  union { float f; unsigned u; } v; v.f = f;
  unsigned r = v.u + 0x7FFFu + ((v.u >> 16) & 1u);
  return (unsigned short)(r >> 16);
}
__device__ __forceinline__ unsigned packbf2(float a, float b){
  return (unsigned)f2bf(a) | ((unsigned)f2bf(b) << 16);
}
__device__ __forceinline__ void gl_lds16(const void* g, const char* l){
  __builtin_amdgcn_global_load_lds(
      (const __attribute__((address_space(1))) void*)g,
      (__attribute__((address_space(3))) void*)(unsigned)(uintptr_t)l,
      16, 0, 0);
}

// ws layouts (per batch, 128 KB each) — FRAGMENT-CONTIGUOUS:
//  qbf : frag[ch][ks][j][64B]   ch=k/64, ks=(k/32)&1, j=0..127
//  qtbf: frag[hch][ks][hr][64B] hch=h/64, ks=j/32,    hr=h&63

// ---------------- K0: Q -> packed bf16 fragments, s_q partials -------------
__global__ __launch_bounds__(256) void k0_prep(const float* __restrict__ Q,
                                               const float* __restrict__ w,
                                               char* __restrict__ qbf,
                                               char* __restrict__ qtbf,
                                               float* __restrict__ sq_part)
{
  __shared__ float tile[128][129];
  __shared__ float sqs[128];
  const int bid = blockIdx.x, t = threadIdx.x;
  const int b = bid >> 2, hc = bid & 3;
  if (t < 128) sqs[t] = 0.f;
  __syncthreads();
  for (int it = 0; it < 16; ++it){
    int idx = it*256 + t;
    int j = idx >> 5, h4 = idx & 31;
    const f32x4 q4 = *(const f32x4*)(Q + ((size_t)b*128 + j)*512 + hc*128 + h4*4);
    *(f32x4*)(&tile[j][h4*4]) = q4;
    unsigned lo = packbf2(q4.x, q4.y), hi = packbf2(q4.z, q4.w);
    int k = hc*128 + h4*4;
    int o = (k >> 6)*16384 + (((k >> 5) & 1))*8192 + j*64 + (k & 31)*2;
    char* dst = qbf + (size_t)b*131072 + o;
    *(unsigned*)dst = lo; *(unsigned*)(dst + 4) = hi;
    const float* w2 = w + 512 + k;
    float p = q4.x*w2[0] + q4.y*w2[1] + q4.z*w2[2] + q4.w*w2[3];
    for (int s = 16; s > 0; s >>= 1) p += __shfl_down(p, s, 32);
    if ((t & 31) == 0) sqs[j] += p;
  }
  __syncthreads();
  for (int it = 0; it < 32; ++it){
    int idx = it*256 + t;
    int hr = idx >> 6, j2 = idx & 63;
    float a = tile[j2*2][hr], c = tile[j2*2+1][hr];
    int h = hc*128 + hr;
    int o = (h >> 6)*16384 + (j2 >> 4)*4096 + (h & 63)*64 + (j2 & 15)*4;
    *(unsigned*)(qtbf + (size_t)b*131072 + o) = packbf2(a, c);
  }
  if (t < 128) sq_part[(size_t)(b*4 + hc)*128 + t] = sqs[t];
}

// -- K1: 4 tiles/block, dbuf C via global_load_lds (zero VGPR staging) ------
__global__ __launch_bounds__(512, 4) void k1_main(
    const float* __restrict__ C, const int* __restrict__ qmask,
    const float* __restrict__ w, const float* __restrict__ sq_part,
    const char* __restrict__ qbf, const char* __restrict__ qtbf,
    float* __restrict__ out, float* __restrict__ num_part,
    float* __restrict__ den_part)
{
  __shared__ __align__(16) char lds_c[2][32768]; // C tiles, swizzled rows
  __shared__ __align__(16) char cw[4096];        // P: 16 rows x 256 B
  __shared__ float w1l[512], w3l[512];
  __shared__ float sqf[128];
  __shared__ int   msk[128];
  __shared__ float exf[16];
  __shared__ float mh[8][16], sh[8][16];

  const int t = threadIdx.x;
  const int bid = blockIdx.x;
  const int xcd = bid & 7, jj = bid >> 3;            // 512 = 8 x 64
  const int b = xcd*4 + (jj >> 4);                   // batch-per-XCD locality
  const int itile0 = (jj & 15)*4;
  const int wv = t >> 6, ln = t & 63;
  const int g = ln >> 4, c16 = ln & 15;
  const int iloc = c16;
  const int swz = ((iloc & 7) << 4) | (((iloc >> 3) & 1) << 7);

  // stage: 32 KB tile of C -> LDS buffer (linear dest, pre-swizzled source)
  auto stageC = [&](int tile_idx, char* dstbuf){
    const char* ct = (const char*)(C + (size_t)(b*1024 + tile_idx*16)*512);
    #pragma unroll
    for (int r = 0; r < 4; ++r){
      const int ob  = wv*4096 + r*1024;
      const int row = ob >> 11;
      const int msw = ((row & 7) << 4) | (((row >> 3) & 1) << 7);
      gl_lds16(ct + ob + ((ln << 4) ^ msw), dstbuf + ob);
    }
  };

  // ---- prologue ----
  stageC(itile0, &lds_c[0][0]);
  if (t < 128){
    sqf[t] = sq_part[(size_t)(b*4 + 0)*128 + t] + sq_part[(size_t)(b*4 + 1)*128 + t]
           + sq_part[(size_t)(b*4 + 2)*128 + t] + sq_part[(size_t)(b*4 + 3)*128 + t];
    msk[t] = qmask[b*128 + t];
  }
  w1l[t] = w[t];
  w3l[t] = w[1024 + t];
  __syncthreads();

  const char* qsrc  = qbf  + (size_t)b * 131072;
  const char* qtsrc = qtbf + (size_t)b * 131072;

  for (int tt = 0; tt < 4; ++tt){
    const char* buf = &lds_c[tt & 1][0];
    const int i0 = (itile0 + tt)*16;
    const size_t rowb = (size_t)(b*1024 + i0 + iloc);

    // ---- S-phase: wave wv computes D[j][i] for j in [wv*16, wv*16+16) ----
    float scp = 0.f;
    f32x4 acc = {};
    #pragma unroll
    for (int ch = 0; ch < 8; ++ch){
      #pragma unroll
      for (int ks = 0; ks < 2; ++ks){
        const int k0 = ch*64 + ks*32 + g*8;
        const int lo = iloc*2048 + k0*4;
        const f32x4 cA  = *(const f32x4*)(buf + (lo ^ swz));
        const f32x4 cB  = *(const f32x4*)(buf + ((lo + 16) ^ swz));
        const f32x4 w3A = *(const f32x4*)(w3l + k0);
        const f32x4 w3B = *(const f32x4*)(w3l + k0 + 4);
        const f32x4 w1A = *(const f32x4*)(w1l + k0);
        const f32x4 w1B = *(const f32x4*)(w1l + k0 + 4);
        scp += cA.x*w1A.x + cA.y*w1A.y + cA.z*w1A.z + cA.w*w1A.w
             + cB.x*w1B.x + cB.y*w1B.y + cB.z*w1B.z + cB.w*w1B.w;
        bf16x8 bv;
        bv[0] = (__bf16)(cA.x*w3A.x); bv[1] = (__bf16)(cA.y*w3A.y);
        bv[2] = (__bf16)(cA.z*w3A.z); bv[3] = (__bf16)(cA.w*w3A.w);
        bv[4] = (__bf16)(cB.x*w3B.x); bv[5] = (__bf16)(cB.y*w3B.y);
        bv[6] = (__bf16)(cB.z*w3B.z); bv[7] = (__bf16)(cB.w*w3B.w);
        const int j = wv*16 + c16;
        bf16x8 av = *(const bf16x8*)(qsrc + ch*16384 + ks*8192 + j*64 + g*16);
        acc = __builtin_amdgcn_mfma_f32_16x16x32_bf16(av, bv, acc, 0, 0, 0);
      }
    }
    scp += __shfl_xor(scp, 16);
    scp += __shfl_xor(scp, 32);
    const float sc = scp;

    // ---- wave-local softmax eighth ----
    float m = -3.0e38f;
    #pragma unroll
    for (int r = 0; r < 4; ++r){
      int j = wv*16 + g*4 + r;
      float v = msk[j] ? (acc[r] + sc + sqf[j]) : NEGV;
      acc[r] = v;
      m = fmaxf(m, v);
    }
    m = fmaxf(m, __shfl_xor(m, 16));
    m = fmaxf(m, __shfl_xor(m, 32));
    float s = 0.f;
    #pragma unroll
    for (int r = 0; r < 4; ++r){
      float e = __expf(acc[r] - m);
      acc[r] = e; s += e;
    }
    s += __shfl_xor(s, 16);
    s += __shfl_xor(s, 32);
    if (g == 0){ mh[wv][iloc] = m; sh[wv][iloc] = s; }
    __syncthreads();

    // ---- 8-way combine ----
    float mF = mh[0][iloc];
    #pragma unroll
    for (int q = 1; q < 8; ++q) mF = fmaxf(mF, mh[q][iloc]);
    float sF = 0.f;
    #pragma unroll
    for (int q = 0; q < 8; ++q) sF += sh[q][iloc]*__expf(mh[q][iloc] - mF);
    const float scale = __expf(m - mF) / sF;
    {
      uint64_t pk = (uint64_t)packbf2(acc[0]*scale, acc[1]*scale)
                  | ((uint64_t)packbf2(acc[2]*scale, acc[3]*scale) << 32);
      *(uint64_t*)(cw + ((iloc*256 + wv*32 + g*8) ^ ((iloc & 7) << 4))) = pk;
    }
    if (wv == 0 && g == 0) exf[iloc] = __expf(mF);
    __syncthreads();   // last mid-tile barrier

    // ---- issue next tile's C stage into idle buffer (zero VGPR, async) ----
    if (tt < 3) stageC(itile0 + tt + 1, &lds_c[(tt & 1) ^ 1][0]);

    // ---- PV: wave wv covers h in [wv*64, wv*64+64); fused epilogue ----
    bf16x8 pb[4];
    #pragma unroll
    for (int ks = 0; ks < 4; ++ks)
      pb[ks] = *(const bf16x8*)(cw + ((iloc*256 + ks*64 + g*16) ^ ((iloc & 7) << 4)));

    f32x4 a2[4] = {};
    #pragma unroll
    for (int nf = 0; nf < 4; ++nf){
      int hr = nf*16 + c16;
      #pragma unroll
      for (int ks = 0; ks < 4; ++ks){
        bf16x8 qa = *(const bf16x8*)(qtsrc + wv*16384 + ks*4096 + hr*64 + g*16);
        a2[nf] = __builtin_amdgcn_mfma_f32_16x16x32_bf16(qa, pb[ks], a2[nf], 0, 0, 0);
      }
    }
    #pragma unroll
    for (int nf = 0; nf < 4; ++nf){
      int h = wv*64 + nf*16 + g*4;
      const int lo = iloc*2048 + h*4;
      const f32x4 c4 = *(const f32x4*)(buf + (lo ^ swz));
      f32x4 av = a2[nf];
      *(f32x4*)(out + rowb*2048 + h)        = c4;        // C copy
      *(f32x4*)(out + rowb*2048 + 512 + h)  = av;        // A
      f32x4 ca = av * c4;
      *(f32x4*)(out + rowb*2048 + 1024 + h) = ca;        // C*A
    }

    // ---- B_vec partials (current buf; exf stable since cw barrier) ----
    float n0 = 0.f;
    #pragma unroll
    for (int i2 = 0; i2 < 16; ++i2){
      const int ms = ((i2 & 7) << 4) | (((i2 >> 3) & 1) << 7);
      n0 += exf[i2] * *(const float*)(buf + ((i2*2048 + t*4) ^ ms));
    }
    num_part[((size_t)(b*64 + itile0 + tt))*512 + t] = n0;
    if (t < 16){
      float d = exf[t];
      d += __shfl_down(d, 8, 16); d += __shfl_down(d, 4, 16);
      d += __shfl_down(d, 2, 16); d += __shfl_down(d, 1, 16);
      if (t == 0) den_part[b*64 + itile0 + tt] = d;
    }
    __syncthreads();   // tile end: drains stage (PV+stores hid latency)
  }
}

// ---------------- K2: reduce partials -> B_vec ------------------------------
__global__ __launch_bounds__(256) void k2_bvec(const float* __restrict__ num_part,
                                               const float* __restrict__ den_part,
                                               float* __restrict__ bvec)
{
  int b = blockIdx.x, t = threadIdx.x;
  float d = 0.f;
  for (int k = 0; k < 64; ++k) d += den_part[b*64 + k];
  float inv = 1.0f / d;
  for (int h = t; h < 512; h += 256){
    float s = 0.f;
    for (int k = 0; k < 64; ++k) s += num_part[(size_t)(b*64 + k)*512 + h];
    bvec[b*512 + h] = s * inv;
  }
}

// ---------------- K3: write C*B_vec chunk -----------------------------------
__global__ __launch_bounds__(256) void k3_cout(const float* __restrict__ C,
                                               const float* __restrict__ bvec,
                                               float* __restrict__ out)
{
  int t = threadIdx.x;
  size_t row = (size_t)blockIdx.x*2 + (t >> 7);
  int col4 = t & 127;
  int b = (int)(row >> 10);
  const f32x4 c4 = *(const f32x4*)(C + row*512 + col4*4);
  const f32x4 bv = *(const f32x4*)(bvec + (size_t)b*512 + col4*4);
  f32x4 cb;
  cb.x = c4.x*bv.x; cb.y = c4.y*bv.y; cb.z = c4.z*bv.z; cb.w = c4.w*bv.w;
  *(f32x4*)(out + row*2048 + 1536 + col4*4) = cb;
}

extern "C" void kernel_launch(void* const* d_in, const int* in_sizes, int n_in,
                              void* d_out, int out_size, void* d_ws, size_t ws_size,
                              hipStream_t stream)
{
  const float* C     = (const float*)d_in[0];
  const float* Q     = (const float*)d_in[1];
  const int*   qmask = (const int*)d_in[2];
  const float* w     = (const float*)d_in[3];
  float* out = (float*)d_out;
  char*  ws  = (char*)d_ws;

  char*  qbf      = ws;                                    // 4 MB
  char*  qtbf     = ws + (4 << 20);                        // 4 MB
  float* sq_part  = (float*)(ws + (8 << 20));              // 64 KB
  float* num_part = (float*)(ws + (8 << 20) + (1 << 16));  // 4 MB
  float* den_part = (float*)(ws + (12 << 20) + (1 << 16)); // 8 KB
  float* bvec     = (float*)(ws + (12 << 20) + (1 << 16) + 8192); // 64 KB

  k0_prep<<<128, 256, 0, stream>>>(Q, w, qbf, qtbf, sq_part);
  k1_main<<<512, 512, 0, stream>>>(C, qmask, w, sq_part, qbf, qtbf,
                                   out, num_part, den_part);
  k2_bvec<<<32, 256, 0, stream>>>(num_part, den_part, bvec);
  k3_cout<<<16384, 256, 0, stream>>>(C, bvec, out);
}

// Round 13
// 123.017 us; speedup vs baseline: 5.0304x; 1.9118x over previous
//
#include <hip/hip_runtime.h>
#include <stdint.h>

#define NEGV (-1000000000.0f)

typedef float  f32x4  __attribute__((ext_vector_type(4)));
typedef __bf16 bf16x8 __attribute__((ext_vector_type(8)));

__device__ __forceinline__ unsigned short f2bf(float f){
  union { float f; unsigned u; } v; v.f = f;
  unsigned r = v.u + 0x7FFFu + ((v.u >> 16) & 1u);
  return (unsigned short)(r >> 16);
}
__device__ __forceinline__ unsigned packbf2(float a, float b){
  return (unsigned)f2bf(a) | ((unsigned)f2bf(b) << 16);
}
__device__ __forceinline__ void gl_lds16(const void* g, const char* l){
  __builtin_amdgcn_global_load_lds(
      (const __attribute__((address_space(1))) void*)g,
      (__attribute__((address_space(3))) void*)(unsigned)(uintptr_t)l,
      16, 0, 0);
}

// ws layouts (per batch, 128 KB each) — FRAGMENT-CONTIGUOUS:
//  qbf : frag[ch][ks][j][64B]   ch=k/64, ks=(k/32)&1, j=0..127
//  qtbf: frag[hch][ks][hr][64B] hch=h/64, ks=j/32,    hr=h&63

// ---------------- K0: Q -> packed bf16 fragments, s_q partials -------------
__global__ __launch_bounds__(256) void k0_prep(const float* __restrict__ Q,
                                               const float* __restrict__ w,
                                               char* __restrict__ qbf,
                                               char* __restrict__ qtbf,
                                               float* __restrict__ sq_part)
{
  __shared__ float tile[128][129];
  __shared__ float sqs[128];
  const int bid = blockIdx.x, t = threadIdx.x;
  const int b = bid >> 2, hc = bid & 3;
  if (t < 128) sqs[t] = 0.f;
  __syncthreads();
  for (int it = 0; it < 16; ++it){
    int idx = it*256 + t;
    int j = idx >> 5, h4 = idx & 31;
    const f32x4 q4 = *(const f32x4*)(Q + ((size_t)b*128 + j)*512 + hc*128 + h4*4);
    *(f32x4*)(&tile[j][h4*4]) = q4;
    unsigned lo = packbf2(q4.x, q4.y), hi = packbf2(q4.z, q4.w);
    int k = hc*128 + h4*4;
    int o = (k >> 6)*16384 + (((k >> 5) & 1))*8192 + j*64 + (k & 31)*2;
    char* dst = qbf + (size_t)b*131072 + o;
    *(unsigned*)dst = lo; *(unsigned*)(dst + 4) = hi;
    const float* w2 = w + 512 + k;
    float p = q4.x*w2[0] + q4.y*w2[1] + q4.z*w2[2] + q4.w*w2[3];
    for (int s = 16; s > 0; s >>= 1) p += __shfl_down(p, s, 32);
    if ((t & 31) == 0) sqs[j] += p;
  }
  __syncthreads();
  for (int it = 0; it < 32; ++it){
    int idx = it*256 + t;
    int hr = idx >> 6, j2 = idx & 63;
    float a = tile[j2*2][hr], c = tile[j2*2+1][hr];
    int h = hc*128 + hr;
    int o = (h >> 6)*16384 + (j2 >> 4)*4096 + (h & 63)*64 + (j2 & 15)*4;
    *(unsigned*)(qtbf + (size_t)b*131072 + o) = packbf2(a, c);
  }
  if (t < 128) sq_part[(size_t)(b*4 + hc)*128 + t] = sqs[t];
}

// -------- K1: R10 structure + VGPR headroom + 2-deep Q prefetch ------------
__global__ __launch_bounds__(512, 4) void k1_main(
    const float* __restrict__ C, const int* __restrict__ qmask,
    const float* __restrict__ w, const float* __restrict__ sq_part,
    const char* __restrict__ qbf, const char* __restrict__ qtbf,
    float* __restrict__ out, float* __restrict__ num_part,
    float* __restrict__ den_part)
{
  __shared__ __align__(16) char lds_c[32768];  // C tile 16 x 2KB, src-swizzled
  __shared__ __align__(16) char cw[4096];      // P: 16 rows x 256 B (swizzled)
  __shared__ float w1l[512], w3l[512];
  __shared__ float sqf[128];
  __shared__ int   msk[128];
  __shared__ float exf[16];
  __shared__ float mh[8][16], sh[8][16];

  const int t = threadIdx.x;
  const int bid = blockIdx.x;
  const int xcd = bid & 7, jj = bid >> 3;            // 2048 = 8 x 256
  const int b = xcd*4 + (jj >> 6), itile = jj & 63;  // batch-per-XCD locality
  const int i0 = itile * 16;
  const int wv = t >> 6, ln = t & 63;
  const int g = ln >> 4, c16 = ln & 15;
  const int iloc = c16;              // 0..15

  // ---- burst-stage the 32 KB C tile (deep vmcnt queue, zero VGPR) ----
  {
    const char* ctile = (const char*)(C + (size_t)(b*1024 + i0)*512);
    #pragma unroll
    for (int r = 0; r < 4; ++r){
      const int ob  = wv*4096 + r*1024;
      const int row = ob >> 11;
      const int msw = ((row & 7) << 4) | (((row >> 3) & 1) << 7);
      gl_lds16(ctile + ob + ((ln << 4) ^ msw), lds_c + ob);
    }
  }
  if (t < 128){
    sqf[t] = sq_part[(size_t)(b*4 + 0)*128 + t] + sq_part[(size_t)(b*4 + 1)*128 + t]
           + sq_part[(size_t)(b*4 + 2)*128 + t] + sq_part[(size_t)(b*4 + 3)*128 + t];
    msk[t] = qmask[b*128 + t];
  }
  w1l[t] = w[t];
  w3l[t] = w[1024 + t];
  __syncthreads();   // drains gload_lds + LDS writes

  const char* qsrc  = qbf  + (size_t)b * 131072;
  const char* qtsrc = qtbf + (size_t)b * 131072;
  const size_t rowb = (size_t)(b*1024 + i0 + iloc);
  const int swz = ((iloc & 7) << 4) | (((iloc >> 3) & 1) << 7);

  // ---- S-phase: flat 16 steps (ch,ks), av prefetched 2 deep ----
  const int j = wv*16 + c16;
  const char* avbase = qsrc + j*64 + g*16;
  float scp = 0.f;
  f32x4 acc = {};
  bf16x8 av0 = *(const bf16x8*)(avbase);          // s=0: ch0,ks0
  bf16x8 av1 = *(const bf16x8*)(avbase + 8192);   // s=1: ch0,ks1
  #pragma unroll
  for (int s5 = 0; s5 < 16; ++s5){
    bf16x8 avc = av0;
    av0 = av1;
    if (s5 < 14){
      const int s2 = s5 + 2;
      av1 = *(const bf16x8*)(avbase + (s2 >> 1)*16384 + (s2 & 1)*8192);
    }
    const int k0 = s5*32 + g*8;
    const int lo = iloc*2048 + k0*4;
    const f32x4 cA  = *(const f32x4*)(lds_c + (lo ^ swz));
    const f32x4 cB  = *(const f32x4*)(lds_c + ((lo + 16) ^ swz));
    const f32x4 w3A = *(const f32x4*)(w3l + k0);
    const f32x4 w3B = *(const f32x4*)(w3l + k0 + 4);
    const f32x4 w1A = *(const f32x4*)(w1l + k0);
    const f32x4 w1B = *(const f32x4*)(w1l + k0 + 4);
    scp += cA.x*w1A.x + cA.y*w1A.y + cA.z*w1A.z + cA.w*w1A.w
         + cB.x*w1B.x + cB.y*w1B.y + cB.z*w1B.z + cB.w*w1B.w;
    bf16x8 bv;
    bv[0] = (__bf16)(cA.x*w3A.x); bv[1] = (__bf16)(cA.y*w3A.y);
    bv[2] = (__bf16)(cA.z*w3A.z); bv[3] = (__bf16)(cA.w*w3A.w);
    bv[4] = (__bf16)(cB.x*w3B.x); bv[5] = (__bf16)(cB.y*w3B.y);
    bv[6] = (__bf16)(cB.z*w3B.z); bv[7] = (__bf16)(cB.w*w3B.w);
    acc = __builtin_amdgcn_mfma_f32_16x16x32_bf16(avc, bv, acc, 0, 0, 0);
  }
  scp += __shfl_xor(scp, 16);
  scp += __shfl_xor(scp, 32);
  const float sc = scp;

  // ---- wave-local softmax eighth ----
  float m = -3.0e38f;
  #pragma unroll
  for (int r = 0; r < 4; ++r){
    int jj2 = wv*16 + g*4 + r;
    float v = msk[jj2] ? (acc[r] + sc + sqf[jj2]) : NEGV;
    acc[r] = v;
    m = fmaxf(m, v);
  }
  m = fmaxf(m, __shfl_xor(m, 16));
  m = fmaxf(m, __shfl_xor(m, 32));
  float s = 0.f;
  #pragma unroll
  for (int r = 0; r < 4; ++r){
    float e = __expf(acc[r] - m);
    acc[r] = e; s += e;
  }
  s += __shfl_xor(s, 16);
  s += __shfl_xor(s, 32);
  if (g == 0){ mh[wv][iloc] = m; sh[wv][iloc] = s; }
  __syncthreads();

  // ---- 8-way combine ----
  float mF = mh[0][iloc];
  #pragma unroll
  for (int q = 1; q < 8; ++q) mF = fmaxf(mF, mh[q][iloc]);
  float sF = 0.f;
  #pragma unroll
  for (int q = 0; q < 8; ++q) sF += sh[q][iloc]*__expf(mh[q][iloc] - mF);
  const float scale = __expf(m - mF) / sF;
  {
    uint64_t pk = (uint64_t)packbf2(acc[0]*scale, acc[1]*scale)
                | ((uint64_t)packbf2(acc[2]*scale, acc[3]*scale) << 32);
    *(uint64_t*)(cw + ((iloc*256 + wv*32 + g*8) ^ ((iloc & 7) << 4))) = pk;
  }
  if (wv == 0 && g == 0) exf[iloc] = __expf(mF);
  __syncthreads();

  // ---- PV: flat 16 steps (nf,ks), qa prefetched 2 deep; fused epilogue ----
  bf16x8 pb[4];
  #pragma unroll
  for (int ks = 0; ks < 4; ++ks)
    pb[ks] = *(const bf16x8*)(cw + ((iloc*256 + ks*64 + g*16) ^ ((iloc & 7) << 4)));

  const char* qabase = qtsrc + wv*16384 + c16*64 + g*16;  // + nf*1024 + ks*4096
  f32x4 a2[4] = {};
  bf16x8 qa0 = *(const bf16x8*)(qabase);           // s=0: nf0,ks0
  bf16x8 qa1 = *(const bf16x8*)(qabase + 4096);    // s=1: nf0,ks1
  #pragma unroll
  for (int s6 = 0; s6 < 16; ++s6){
    bf16x8 qac = qa0;
    qa0 = qa1;
    if (s6 < 14){
      const int s2 = s6 + 2;
      qa1 = *(const bf16x8*)(qabase + (s2 >> 2)*1024 + (s2 & 3)*4096);
    }
    a2[s6 >> 2] = __builtin_amdgcn_mfma_f32_16x16x32_bf16(qac, pb[s6 & 3], a2[s6 >> 2], 0, 0, 0);
  }
  #pragma unroll
  for (int nf = 0; nf < 4; ++nf){
    int h = wv*64 + nf*16 + g*4;
    const int lo = iloc*2048 + h*4;
    const f32x4 c4 = *(const f32x4*)(lds_c + (lo ^ swz));
    f32x4 av = a2[nf];
    *(f32x4*)(out + rowb*2048 + h)        = c4;        // C copy
    *(f32x4*)(out + rowb*2048 + 512 + h)  = av;        // A
    f32x4 ca = av * c4;
    *(f32x4*)(out + rowb*2048 + 1024 + h) = ca;        // C*A
  }

  // exf stable since the P-barrier; stores drain async

  // ---- B_vec partials: 512 threads, one h column each, 16 rows from LDS ----
  float n0 = 0.f;
  #pragma unroll
  for (int i2 = 0; i2 < 16; ++i2){
    const int ms = ((i2 & 7) << 4) | (((i2 >> 3) & 1) << 7);
    n0 += exf[i2] * *(const float*)(lds_c + ((i2*2048 + t*4) ^ ms));
  }
  num_part[((size_t)(b*64 + itile))*512 + t] = n0;
  if (t < 16){
    float d = exf[t];
    d += __shfl_down(d, 8, 16); d += __shfl_down(d, 4, 16);
    d += __shfl_down(d, 2, 16); d += __shfl_down(d, 1, 16);
    if (t == 0) den_part[b*64 + itile] = d;
  }
}

// ---------------- K2: reduce partials -> B_vec ------------------------------
__global__ __launch_bounds__(256) void k2_bvec(const float* __restrict__ num_part,
                                               const float* __restrict__ den_part,
                                               float* __restrict__ bvec)
{
  int b = blockIdx.x, t = threadIdx.x;
  float d = 0.f;
  for (int k = 0; k < 64; ++k) d += den_part[b*64 + k];
  float inv = 1.0f / d;
  for (int h = t; h < 512; h += 256){
    float s = 0.f;
    for (int k = 0; k < 64; ++k) s += num_part[(size_t)(b*64 + k)*512 + h];
    bvec[b*512 + h] = s * inv;
  }
}

// ---------------- K3: write C*B_vec chunk -----------------------------------
__global__ __launch_bounds__(256) void k3_cout(const float* __restrict__ C,
                                               const float* __restrict__ bvec,
                                               float* __restrict__ out)
{
  int t = threadIdx.x;
  size_t row = (size_t)blockIdx.x*2 + (t >> 7);
  int col4 = t & 127;
  int b = (int)(row >> 10);
  const f32x4 c4 = *(const f32x4*)(C + row*512 + col4*4);
  const f32x4 bv = *(const f32x4*)(bvec + (size_t)b*512 + col4*4);
  f32x4 cb;
  cb.x = c4.x*bv.x; cb.y = c4.y*bv.y; cb.z = c4.z*bv.z; cb.w = c4.w*bv.w;
  *(f32x4*)(out + row*2048 + 1536 + col4*4) = cb;
}

extern "C" void kernel_launch(void* const* d_in, const int* in_sizes, int n_in,
                              void* d_out, int out_size, void* d_ws, size_t ws_size,
                              hipStream_t stream)
{
  const float* C     = (const float*)d_in[0];
  const float* Q     = (const float*)d_in[1];
  const int*   qmask = (const int*)d_in[2];
  const float* w     = (const float*)d_in[3];
  float* out = (float*)d_out;
  char*  ws  = (char*)d_ws;

  char*  qbf      = ws;                                    // 4 MB
  char*  qtbf     = ws + (4 << 20);                        // 4 MB
  float* sq_part  = (float*)(ws + (8 << 20));              // 64 KB
  float* num_part = (float*)(ws + (8 << 20) + (1 << 16));  // 4 MB
  float* den_part = (float*)(ws + (12 << 20) + (1 << 16)); // 8 KB
  float* bvec     = (float*)(ws + (12 << 20) + (1 << 16) + 8192); // 64 KB

  k0_prep<<<128, 256, 0, stream>>>(Q, w, qbf, qtbf, sq_part);
  k1_main<<<2048, 512, 0, stream>>>(C, qmask, w, sq_part, qbf, qtbf,
                                    out, num_part, den_part);
  k2_bvec<<<32, 256, 0, stream>>>(num_part, den_part, bvec);
  k3_cout<<<16384, 256, 0, stream>>>(C, bvec, out);
}